// Round 9
// baseline (338.140 us; speedup 1.0000x reference)
//
#include <hip/hip_runtime.h>
#include <stdint.h>

#define TEMPERATURE 0.07f
#define MARGIN 0.1f
#define D_DIM 512          // elements per row
#define BM 128
#define BN 256
#define QSCALE 32.0f       // pre-quantization scale (2^5)
#define SCALE_BYTE 0x7A7A7A7A  // e8m0 2^-5 replicated (compensates QSCALE^2)
#define KS_STRIDE 524288   // bytes per K-step slab: 1024 panels * 512 B

// FP4 (e2m1) packed layout, ks-major (per matrix, N*256 bytes = 4 MB):
//   nibble(row,k) -> byte  (k>>6)*KS_STRIDE + (row>>4)*512
//                        + ((k>>5)&1)*256 + (row&15)*16 + ((k&31)>>1)
//   (k even = low nibble; within-lane k order is irrelevant: both operands
//    use the identical packing, so any k permutation cancels in the dot.)
// mfma_scale_f32_32x32x64_f8f6f4 (cbsz=blgp=4 -> FP4) lane-L fragment of a
// pair-region (32 rows, 1024 B per K-step) at kstep ks: 16 B at
//   ks*KS_STRIDE + pair*1024 + ((L>>4)&1)*512 + (L>>5)*256 + (L&15)*16
// Register-direct feed for BOTH operands; single-buffered fragments +
// __launch_bounds__(256,3): 3 waves/SIMD so TLP (not ILP) hides L2 latency.

typedef int v8i32 __attribute__((ext_vector_type(8)));
typedef int v4i32 __attribute__((ext_vector_type(4)));
typedef float f32x16 __attribute__((ext_vector_type(16)));

__device__ __forceinline__ float softplus(float x) {
    return fmaxf(x, 0.0f) + __logf(1.0f + __expf(-fabsf(x)));
}

// e2m1 round-to-nearest encode. Levels: 0,.5,1,1.5,2,3,4,6 (codes 0..7).
__device__ __forceinline__ unsigned enc_fp4(float v) {
    const float ay = fabsf(v);
    int c = 0;
    c += ay > 0.25f;
    c += ay > 0.75f;
    c += ay > 1.25f;
    c += ay > 1.75f;
    c += ay > 2.5f;
    c += ay > 3.5f;
    c += ay > 5.0f;
    return (unsigned)c | ((__float_as_uint(v) >> 28) & 8u);
}

// Fused: L2-normalize row of S and T, quantize to e2m1 fp4 (x32), write the
// ks-major packed layout (via LDS so global writes are contiguous 512-B
// pieces — measured faster than direct scattered stores), and atomically
// accumulate the per-block (16-row) corr sum into the global accumulator.
__global__ __launch_bounds__(1024) void norm_quant_pack_kernel(
    const float* __restrict__ s_in, const float* __restrict__ t_in,
    unsigned char* __restrict__ sp, unsigned char* __restrict__ tp,
    float* __restrict__ accum) {
    __shared__ unsigned pls[2048];  // words: [0,1024) S panel, [1024,2048) T
    __shared__ float cshr[16];
    const int wave = threadIdx.x >> 6;
    const int lane = threadIdx.x & 63;
    const int row = blockIdx.x * 16 + wave;
    const float4* s4 = (const float4*)(s_in + (size_t)row * D_DIM);
    const float4* t4 = (const float4*)(t_in + (size_t)row * D_DIM);
    float4 a0 = s4[lane * 2], a1 = s4[lane * 2 + 1];
    float4 b0 = t4[lane * 2], b1 = t4[lane * 2 + 1];
    float ss = a0.x * a0.x + a0.y * a0.y + a0.z * a0.z + a0.w * a0.w +
               a1.x * a1.x + a1.y * a1.y + a1.z * a1.z + a1.w * a1.w;
    float tt = b0.x * b0.x + b0.y * b0.y + b0.z * b0.z + b0.w * b0.w +
               b1.x * b1.x + b1.y * b1.y + b1.z * b1.z + b1.w * b1.w;
    float st = a0.x * b0.x + a0.y * b0.y + a0.z * b0.z + a0.w * b0.w +
               a1.x * b1.x + a1.y * b1.y + a1.z * b1.z + a1.w * b1.w;
#pragma unroll
    for (int off = 32; off > 0; off >>= 1) {
        ss += __shfl_down(ss, off);
        tt += __shfl_down(tt, off);
        st += __shfl_down(st, off);
    }
    ss = __shfl(ss, 0);
    tt = __shfl(tt, 0);
    const float ns = fmaxf(sqrtf(ss), 1e-12f);
    const float nt = fmaxf(sqrtf(tt), 1e-12f);
    if (lane == 0) {
        const float l = st / (ns * nt) * (1.0f / TEMPERATURE);
        cshr[wave] = softplus(-l - MARGIN) - softplus(l - MARGIN);
    }
    const float is = QSCALE / ns, it = QSCALE / nt;
    // 8 elems (k = 8*lane .. 8*lane+7) -> one u32 of nibbles, k ascending.
    const unsigned ws_ = enc_fp4(a0.x * is) | (enc_fp4(a0.y * is) << 4) |
                         (enc_fp4(a0.z * is) << 8) | (enc_fp4(a0.w * is) << 12) |
                         (enc_fp4(a1.x * is) << 16) | (enc_fp4(a1.y * is) << 20) |
                         (enc_fp4(a1.z * is) << 24) | (enc_fp4(a1.w * is) << 28);
    const unsigned wt_ = enc_fp4(b0.x * it) | (enc_fp4(b0.y * it) << 4) |
                         (enc_fp4(b0.z * it) << 8) | (enc_fp4(b0.w * it) << 12) |
                         (enc_fp4(b1.x * it) << 16) | (enc_fp4(b1.y * it) << 20) |
                         (enc_fp4(b1.z * it) << 24) | (enc_fp4(b1.w * it) << 28);
    // word index: ks(=lane>>3)*128 + khalf(=(lane>>2)&1)*64 + row*4 + (lane&3)
    const int widx =
        (lane >> 3) * 128 + ((lane >> 2) & 1) * 64 + wave * 4 + (lane & 3);
    pls[widx] = ws_;
    pls[1024 + widx] = wt_;
    __syncthreads();
    const int t = threadIdx.x;
    const int ks = t >> 7, rem = t & 127;
    const size_t goff = (size_t)ks * KS_STRIDE + (size_t)blockIdx.x * 512 +
                        (size_t)rem * 4;
    *(unsigned*)(sp + goff) = pls[t];
    *(unsigned*)(tp + goff) = pls[1024 + t];
    if (t == 0) {
        float c = 0.0f;
#pragma unroll
        for (int w = 0; w < 16; ++w) c += cshr[w];
        atomicAdd(accum, c);
    }
}

// 128x256 logits tile per block; 4 waves 2x2, wave tile 64x128 = 2x4 of
// FP4 mfma_scale_f32_32x32x64_f8f6f4 (cbsz=blgp=4). BOTH operands
// register-direct from global (L2-resident; 16-B loads), SINGLE-buffered
// fragments so 3 waves/SIMD fit (TLP hides L2 latency). No LDS staging,
// no barriers, no manual waitcnt. Final reduction fused: per-block
// atomicAdd + ticket counter; last block writes out[0] = accum / N.
__global__ __launch_bounds__(256, 3) void gemm_loss_kernel(
    const unsigned char* __restrict__ Sp, const unsigned char* __restrict__ Tp,
    float* __restrict__ accum, unsigned* __restrict__ ticket,
    float* __restrict__ out, float invN) {
    __shared__ float wsums[4];

    const int tid = threadIdx.x;
    const int wave = tid >> 6;
    const int lane = tid & 63;
    const int wm = wave >> 1;   // 0..1 (M)
    const int wn = wave & 1;    // 0..1 (N)

    // XCD super-tile swizzle (grid 8192 = 128x64 tiles; 16x4-block super-tile
    // per XCD -> S+T fp4 panels L2-resident).
    const int b = blockIdx.x;
    const int xcd = b & 7;
    const int slot = b >> 3;
    const int sidx = slot >> 6;
    const int within = slot & 63;
    const int st_ = sidx * 8 + xcd;
    const int tm = (st_ >> 4) * 16 + (within >> 2);   // 0..127
    const int tn_ = (st_ & 15) * 4 + (within & 3);    // 0..63

    // Per-lane fp4 fragment offset within a pair-region (1024 B)
    const int fl4 =
        ((lane >> 4) & 1) * 512 + (lane >> 5) * 256 + (lane & 15) * 16;

    // A pairs = tm*4 + wm*2 + {0,1};  B pairs = tn_*8 + wn*4 + {0..3}
    const unsigned char* Ab = Sp + (size_t)(tm * 4 + wm * 2) * 1024 + fl4;
    const unsigned char* Bb = Tp + (size_t)(tn_ * 8 + wn * 4) * 1024 + fl4;

    f32x16 acc[2][4];
#pragma unroll
    for (int pa = 0; pa < 2; ++pa)
#pragma unroll
        for (int pb = 0; pb < 4; ++pb)
#pragma unroll
            for (int r = 0; r < 16; ++r) acc[pa][pb][r] = 0.0f;

#pragma unroll
    for (int ks = 0; ks < 8; ++ks) {
        const size_t ko = (size_t)ks * KS_STRIDE;
        v4i32 aF[2], bF[4];
#pragma unroll
        for (int pa = 0; pa < 2; ++pa)
            aF[pa] = *(const v4i32*)(Ab + ko + pa * 1024);
#pragma unroll
        for (int pb = 0; pb < 4; ++pb)
            bF[pb] = *(const v4i32*)(Bb + ko + pb * 1024);
        // fp4 operands live in regs 0-3; upper half undef (HW ignores it).
        v8i32 aX[2];
#pragma unroll
        for (int pa = 0; pa < 2; ++pa)
            aX[pa] = __builtin_shufflevector(aF[pa], aF[pa], 0, 1, 2, 3, -1,
                                             -1, -1, -1);
#pragma unroll
        for (int pb = 0; pb < 4; ++pb) {
            v8i32 bX = __builtin_shufflevector(bF[pb], bF[pb], 0, 1, 2, 3, -1,
                                               -1, -1, -1);
#pragma unroll
            for (int pa = 0; pa < 2; ++pa)
                acc[pa][pb] = __builtin_amdgcn_mfma_scale_f32_32x32x64_f8f6f4(
                    aX[pa], bX, acc[pa][pb], 4 /*fp4*/, 4 /*fp4*/,
                    0, SCALE_BYTE, 0, SCALE_BYTE);
        }
    }

    // Uniform epilogue: sum softplus(logit - margin) over all elems.
    // softplus(z) = ln2*( (y+|y|)/2 + log2(1+2^(-|y|)) ), y = z*log2e;
    // log2 terms folded into one v_log per 16-elem group via a product.
    const float C1 = (1.0f / TEMPERATURE) * 1.4426950408889634f;  // log2e/T
    const float C2 = -MARGIN * 1.4426950408889634f;
    float ysum = 0.0f, asum = 0.0f, lsum = 0.0f;
#pragma unroll
    for (int pa = 0; pa < 2; ++pa)
#pragma unroll
        for (int pb = 0; pb < 4; ++pb) {
            float prod = 1.0f;
#pragma unroll
            for (int r = 0; r < 16; ++r) {
                const float y = fmaf(acc[pa][pb][r], C1, C2);
                ysum += y;
                const float ay = fabsf(y);
                asum += ay;
                prod = fmaf(prod, __builtin_amdgcn_exp2f(-ay), prod);
            }
            lsum += __builtin_amdgcn_logf(prod);
        }
    float total =
        fmaf(ysum + asum, 0.5f, lsum) * 0.6931471805599453f;  // * ln2
#pragma unroll
    for (int off = 32; off > 0; off >>= 1) total += __shfl_down(total, off);
    if (lane == 0) wsums[wave] = total;
    __syncthreads();
    if (tid == 0) {
        const float t = wsums[0] + wsums[1] + wsums[2] + wsums[3];
        atomicAdd(accum, t);
        __threadfence();
        const unsigned got = atomicAdd(ticket, 1u);
        if (got == gridDim.x - 1) {
            const float full = atomicAdd(accum, 0.0f);  // coherent read
            out[0] = full * invN;
        }
    }
}

extern "C" void kernel_launch(void* const* d_in, const int* in_sizes, int n_in,
                              void* d_out, int out_size, void* d_ws, size_t ws_size,
                              hipStream_t stream) {
    (void)n_in; (void)out_size; (void)ws_size;
    const float* s_in = (const float*)d_in[0];
    const float* t_in = (const float*)d_in[1];
    const int N = in_sizes[0] / D_DIM;  // 16384

    unsigned char* sp = (unsigned char*)d_ws;                    // N*256 fp4 packed
    unsigned char* tp = sp + (size_t)N * (D_DIM / 2);            // N*256 fp4 packed
    float* accum = (float*)(tp + (size_t)N * (D_DIM / 2));       // 1 float
    unsigned* ticket = (unsigned*)(accum + 1);                   // 1 uint
    const int nBlocks = (N / BM) * (N / BN);                     // 8192

    hipMemsetAsync(accum, 0, 8, stream);  // zero accum + ticket
    norm_quant_pack_kernel<<<N / 16, 1024, 0, stream>>>(s_in, t_in, sp, tp,
                                                        accum);
    gemm_loss_kernel<<<nBlocks, 256, 0, stream>>>(sp, tp, accum, ticket,
                                                  (float*)d_out,
                                                  1.0f / (float)N);
}